// Round 5
// baseline (5800.603 us; speedup 1.0000x reference)
//
#include <hip/hip_runtime.h>
#include <math.h>

#define NB   256   // batch
#define TT   512   // seq len
#define VIN  64
#define EE   64
#define HH   128
#define G4   (4*HH)   // 512 gates per layer
#define VOUT 128
#define RPB  2        // rows per block
#define NWG  (NB/RPB) // 128 workgroups
#define NTHR 256      // threads per block: (r,u) = 2 x 128
#define KC   64       // k-rows of Wh0 cached in LDS (128 KB)

// Gate-quad packed weights: [k][u] -> {W[u][k], W[u+H][k], W[u+2H][k], W[u+3H][k]}
__device__ float4 g_W4x0[EE*HH];        // 128 KB
__device__ float4 g_W4h0[HH*HH];        // 256 KB
__device__ float4 g_W4x1[HH*HH];        // 256 KB
__device__ float4 g_W4h1[HH*HH];        // 256 KB
// Wout packed over k-quads: [k4][v] = {Wout[v][4k4+0..3]}
__device__ float4 g_Wo4[(HH/4)*VOUT];   // 64 KB
// Precomputed layer-0 input gates: [(b*TT+t)*HH + u] quad  (256 MB, static)
__device__ float4 g_gx4[(size_t)NB*TT*HH];

__global__ __launch_bounds__(256) void prep_kernel(
    const float* __restrict__ Wx0, const float* __restrict__ Wh0,
    const float* __restrict__ Wx1, const float* __restrict__ Wh1,
    const float* __restrict__ Wout)
{
  int i = blockIdx.x * 256 + threadIdx.x;   // grid covers 16384
  if (i < EE*HH) {
    int e = i / HH, u = i % HH;
    g_W4x0[i] = make_float4(Wx0[u*EE+e], Wx0[(u+HH)*EE+e],
                            Wx0[(u+2*HH)*EE+e], Wx0[(u+3*HH)*EE+e]);
  }
  if (i < HH*HH) {
    int k = i / HH, u = i % HH;
    g_W4h0[i] = make_float4(Wh0[u*HH+k], Wh0[(u+HH)*HH+k],
                            Wh0[(u+2*HH)*HH+k], Wh0[(u+3*HH)*HH+k]);
    g_W4x1[i] = make_float4(Wx1[u*HH+k], Wx1[(u+HH)*HH+k],
                            Wx1[(u+2*HH)*HH+k], Wx1[(u+3*HH)*HH+k]);
    g_W4h1[i] = make_float4(Wh1[u*HH+k], Wh1[(u+HH)*HH+k],
                            Wh1[(u+2*HH)*HH+k], Wh1[(u+3*HH)*HH+k]);
  }
  if (i < (HH/4)*VOUT) {
    int k4 = i / VOUT, v = i % VOUT;
    g_Wo4[i] = make_float4(Wout[v*HH+4*k4+0], Wout[v*HH+4*k4+1],
                           Wout[v*HH+4*k4+2], Wout[v*HH+4*k4+3]);
  }
}

__device__ __forceinline__ float sigf(float x) {
  return 1.0f / (1.0f + expf(-x));
}

// one float4 = 4 gate weights for the same (k,u); 4 FMAs per 16B load.
// (was a macro; macro param `w` collided with float4 member `.w`)
__device__ __forceinline__ void gq_fma(float4& acc, float xs, float4 wq) {
  acc.x = fmaf(xs, wq.x, acc.x);
  acc.y = fmaf(xs, wq.y, acc.y);
  acc.z = fmaf(xs, wq.z, acc.z);
  acc.w = fmaf(xs, wq.w, acc.w);
}

// ---------------------------------------------------------------------------
// Precompute g_gx4[b][t][u] = bx0_quad[u] + Wx0_quad . emb[src[b,t]].
// One block per batch row; Wx0 (128 KB) LDS-resident; groups of 8 timesteps
// with block-uniform skip past len; halves of the block take 4 tokens each.
// ---------------------------------------------------------------------------
__global__ __launch_bounds__(256) void xproj_kernel(
    const int*   __restrict__ src,  const int* __restrict__ lens,
    const float* __restrict__ emb,  const float* __restrict__ bx0)
{
  __shared__ float4 s_w[EE*HH];    // 128 KB: [e][u] gate quads
  __shared__ float4 s_x4[8][EE/4]; // 2 KB: 8 tokens x 16 float4

  const int b    = blockIdx.x;
  const int tid  = threadIdx.x;
  const int u    = tid & 127;
  const int half = tid >> 7;       // 0/1 -> tokens 0-3 / 4-7

  for (int i = tid; i < EE*HH; i += 256) s_w[i] = g_W4x0[i];
  const int len = lens[b];
  const float4 bq = make_float4(bx0[u], bx0[u+HH], bx0[u+2*HH], bx0[u+3*HH]);
  const float4* __restrict__ emb4 = (const float4*)emb;
  __syncthreads();

  for (int t0 = 0; t0 < TT; t0 += 8) {
    if (t0 >= len) break;                       // block-uniform skip
    __syncthreads();                            // prev group's s_x4 reads done
    if (tid < 128) {
      int p  = tid >> 4;                        // token slot 0..7
      int e4 = tid & 15;
      int tok = src[b*TT + t0 + p];
      s_x4[p][e4] = emb4[tok*(EE/4) + e4];
    }
    __syncthreads();

    float4 a0 = bq, a1 = bq, a2 = bq, a3 = bq;
    #pragma unroll
    for (int e4 = 0; e4 < EE/4; ++e4) {
      float4 w0 = s_w[(e4*4+0)*HH + u];
      float4 w1 = s_w[(e4*4+1)*HH + u];
      float4 w2 = s_w[(e4*4+2)*HH + u];
      float4 w3 = s_w[(e4*4+3)*HH + u];
      float4 x0 = s_x4[half*4+0][e4];
      float4 x1 = s_x4[half*4+1][e4];
      float4 x2 = s_x4[half*4+2][e4];
      float4 x3 = s_x4[half*4+3][e4];
      gq_fma(a0, x0.x, w0); gq_fma(a0, x0.y, w1); gq_fma(a0, x0.z, w2); gq_fma(a0, x0.w, w3);
      gq_fma(a1, x1.x, w0); gq_fma(a1, x1.y, w1); gq_fma(a1, x1.z, w2); gq_fma(a1, x1.w, w3);
      gq_fma(a2, x2.x, w0); gq_fma(a2, x2.y, w1); gq_fma(a2, x2.z, w2); gq_fma(a2, x2.w, w3);
      gq_fma(a3, x3.x, w0); gq_fma(a3, x3.y, w1); gq_fma(a3, x3.z, w2); gq_fma(a3, x3.w, w3);
    }
    size_t base = ((size_t)b*TT + t0 + half*4) * HH + u;
    g_gx4[base + 0*HH] = a0;
    g_gx4[base + 1*HH] = a1;
    g_gx4[base + 2*HH] = a2;
    g_gx4[base + 3*HH] = a3;
  }
}

// ---------------------------------------------------------------------------
// Recurrent kernel: 2 rows x 128 units = 256 threads. Writes h1 states into
// d_out (proj_kernel converts them to logits in-place afterwards).
// ---------------------------------------------------------------------------
__global__ __launch_bounds__(NTHR) void lstm_kernel(
    const int*   __restrict__ lens,
    const float* __restrict__ bx1,
    float*       __restrict__ out)
{
  __shared__ float4 s_wh0c[KC*HH];     // 128 KB: Wh0 rows k < KC
  __shared__ float  s_h0[2][RPB][HH];  // 2 KB (ping-pong)
  __shared__ float  s_h1[2][RPB][HH];  // 2 KB
  __shared__ float  s_bx1[G4];         // 2 KB
  __shared__ int    s_len[RPB];

  const int tid = threadIdx.x;
  const int r   = tid >> 7;        // row within block (wave-uniform)
  const int u   = tid & 127;       // hidden unit
  const int row = blockIdx.x * RPB;

  for (int i = tid; i < KC*HH; i += NTHR) s_wh0c[i] = g_W4h0[i];
  for (int i = tid; i < G4;    i += NTHR) s_bx1[i]  = bx1[i];
  if (tid < RPB) s_len[tid] = lens[row + tid];
  s_h0[0][r][u] = 0.0f; s_h0[1][r][u] = 0.0f;
  s_h1[0][r][u] = 0.0f; s_h1[1][r][u] = 0.0f;
  __syncthreads();

  const int len_r  = s_len[r];
  const int maxlen = max(s_len[0], s_len[1]);
  float c0 = 0.0f, c1 = 0.0f;      // cell states thread-private
  float h1keep = 0.0f;             // frozen h1 for masked steps
  float* outrow = out + (size_t)(row + r) * TT * HH;

  const float4 b1q = make_float4(s_bx1[u], s_bx1[u+HH], s_bx1[u+2*HH], s_bx1[u+3*HH]);
  const float4* __restrict__ wh0 = g_W4h0 + u;
  const float4* __restrict__ wx1 = g_W4x1 + u;
  const float4* __restrict__ wh1 = g_W4h1 + u;
  const float4* __restrict__ gxr = g_gx4 + (size_t)(row + r) * TT * HH + u;

  for (int t = 0; t < maxlen; ++t) {
    const int  pp  = t & 1;        // read buffer; write to pp^1
    const bool act = (t < len_r);

    // ---------- layer 0 (x-projection precomputed) ----------
    if (act) {
      float4 a = gxr[(size_t)t * HH];
      #pragma unroll 4
      for (int k = 0; k < KC; k += 4) {          // LDS-cached half of Wh0
        float4 h4 = *(const float4*)(&s_h0[pp][r][k]);
        float4 w0 = s_wh0c[(k+0)*HH + u], w1 = s_wh0c[(k+1)*HH + u];
        float4 w2 = s_wh0c[(k+2)*HH + u], w3 = s_wh0c[(k+3)*HH + u];
        gq_fma(a, h4.x, w0); gq_fma(a, h4.y, w1);
        gq_fma(a, h4.z, w2); gq_fma(a, h4.w, w3);
      }
      #pragma unroll 4
      for (int k = KC; k < HH; k += 4) {         // streamed half of Wh0
        float4 h4 = *(const float4*)(&s_h0[pp][r][k]);
        float4 w0 = wh0[(k+0)*HH], w1 = wh0[(k+1)*HH];
        float4 w2 = wh0[(k+2)*HH], w3 = wh0[(k+3)*HH];
        gq_fma(a, h4.x, w0); gq_fma(a, h4.y, w1);
        gq_fma(a, h4.z, w2); gq_fma(a, h4.w, w3);
      }
      float i_ = sigf(a.x), f_ = sigf(a.y), g_ = tanhf(a.z), o_ = sigf(a.w);
      c0 = fmaf(f_, c0, i_ * g_);
      float h0n = o_ * tanhf(c0);
      s_h0[pp^1][r][u] = h0n;      // write other buffer: no read-hazard
    }
    __syncthreads();               // new h0 visible to both waves of row r

    // ---------- layer 1 ----------
    if (act) {
      float4 a = b1q;
      #pragma unroll 4
      for (int k = 0; k < HH; k += 4) {
        float4 x4 = *(const float4*)(&s_h0[pp^1][r][k]);
        float4 w0 = wx1[(k+0)*HH], w1 = wx1[(k+1)*HH];
        float4 w2 = wx1[(k+2)*HH], w3 = wx1[(k+3)*HH];
        gq_fma(a, x4.x, w0); gq_fma(a, x4.y, w1);
        gq_fma(a, x4.z, w2); gq_fma(a, x4.w, w3);
      }
      #pragma unroll 4
      for (int k = 0; k < HH; k += 4) {
        float4 h4 = *(const float4*)(&s_h1[pp][r][k]);
        float4 w0 = wh1[(k+0)*HH], w1 = wh1[(k+1)*HH];
        float4 w2 = wh1[(k+2)*HH], w3 = wh1[(k+3)*HH];
        gq_fma(a, h4.x, w0); gq_fma(a, h4.y, w1);
        gq_fma(a, h4.z, w2); gq_fma(a, h4.w, w3);
      }
      float i_ = sigf(a.x), f_ = sigf(a.y), g_ = tanhf(a.z), o_ = sigf(a.w);
      c1 = fmaf(f_, c1, i_ * g_);
      float h1n = o_ * tanhf(c1);
      s_h1[pp^1][r][u] = h1n;
      h1keep = h1n;
    }
    outrow[(size_t)t * HH + u] = h1keep;   // h1 (frozen for inactive rows)
    __syncthreads();               // new h1 visible to both waves of row r
  }

  // barrier-free tail: logits (h1) frozen for t >= maxlen
  for (int t = maxlen; t < TT; ++t)
    outrow[(size_t)t * HH + u] = h1keep;
}

// ---------------------------------------------------------------------------
// In-place projection: d_out rows h1 -> logits. One wave per (b,t) row; each
// lane computes logits u=lane and u=lane+64. Loads->compute->stores ordering
// within the wave is enforced by data dependence (no cross-wave sharing).
// ---------------------------------------------------------------------------
__global__ __launch_bounds__(256) void proj_kernel(
    const float* __restrict__ bout, float* __restrict__ out)
{
  __shared__ float4 s_wo[(HH/4)*VOUT];   // 64 KB
  __shared__ float  s_bout[VOUT];

  const int tid  = threadIdx.x;
  const int wid  = tid >> 6;             // wave 0..3
  const int lane = tid & 63;

  for (int i = tid; i < (HH/4)*VOUT; i += 256) s_wo[i] = g_Wo4[i];
  if (tid < VOUT) s_bout[tid] = bout[tid];
  __syncthreads();

  const int PPB = (NB*TT) / 256;         // 512 rows per block
  const int start = blockIdx.x * PPB;
  for (int it = 0; it < PPB/4; ++it) {
    const int pair = start + it*4 + wid;
    float* rowp = out + (size_t)pair * HH;
    float v0 = s_bout[lane], v1 = s_bout[lane + 64];
    #pragma unroll 8
    for (int k4 = 0; k4 < HH/4; ++k4) {
      float4 h4 = *(const float4*)(rowp + k4*4);   // wave-uniform, L1-broadcast
      float4 w0 = s_wo[k4*VOUT + lane];
      float4 w1 = s_wo[k4*VOUT + lane + 64];
      v0 = fmaf(h4.x,w0.x, fmaf(h4.y,w0.y, fmaf(h4.z,w0.z, fmaf(h4.w,w0.w, v0))));
      v1 = fmaf(h4.x,w1.x, fmaf(h4.y,w1.y, fmaf(h4.z,w1.z, fmaf(h4.w,w1.w, v1))));
    }
    rowp[lane]      = v0;
    rowp[lane + 64] = v1;
  }
}

extern "C" void kernel_launch(void* const* d_in, const int* in_sizes, int n_in,
                              void* d_out, int out_size, void* d_ws, size_t ws_size,
                              hipStream_t stream) {
  const int*   src  = (const int*)  d_in[0];
  const int*   lens = (const int*)  d_in[1];
  const float* emb  = (const float*)d_in[2];
  const float* Wx0  = (const float*)d_in[3];
  const float* bx0  = (const float*)d_in[4];
  const float* Wh0  = (const float*)d_in[5];
  const float* Wx1  = (const float*)d_in[6];
  const float* bx1  = (const float*)d_in[7];
  const float* Wh1  = (const float*)d_in[8];
  const float* Wout = (const float*)d_in[9];
  const float* bout = (const float*)d_in[10];
  float* out = (float*)d_out;

  hipLaunchKernelGGL(prep_kernel, dim3(64), dim3(256), 0, stream,
                     Wx0, Wh0, Wx1, Wh1, Wout);
  hipLaunchKernelGGL(xproj_kernel, dim3(NB), dim3(256), 0, stream,
                     src, lens, emb, bx0);
  hipLaunchKernelGGL(lstm_kernel, dim3(NWG), dim3(NTHR), 0, stream,
                     lens, bx1, out);
  hipLaunchKernelGGL(proj_kernel, dim3(256), dim3(256), 0, stream,
                     bout, out);
}

// Round 7
// 5622.069 us; speedup vs baseline: 1.0318x; 1.0318x over previous
//
#include <hip/hip_runtime.h>
#include <hip/hip_fp16.h>
#include <math.h>

#define NB   256   // batch
#define TT   512   // seq len
#define EE   64
#define HH   128
#define G4   (4*HH)
#define VOUT 128
#define RPB  2        // rows per block
#define NWG  (NB/RPB) // 128 workgroups
#define NTHR 512      // threads: (r,u,kh) = 2 x 128 x 2
#define NRP  (HH/2)   // 64 row-pairs per matrix

// fp32 packs (used by the parallel kernels only)
__device__ float4 g_W4x0[EE*HH];        // [e][u] gate quads, 128 KB
__device__ float4 g_Wo4[(HH/4)*VOUT];   // [k4][v], 64 KB
// fp16 row-pair packs for the recurrent loop: entry[rp][u] = 16 B =
// { quad(k=2rp,u) , quad(k=2rp+1,u) }, quad = {W[u][k],W[u+H][k],W[u+2H][k],W[u+3H][k]}
__device__ uint4  g_h016[NRP*HH];       // Wh0, 131 KB
__device__ uint4  g_x116[NRP*HH];       // Wx1, 131 KB
__device__ uint4  g_h116[NRP*HH];       // Wh1, 131 KB
// Precomputed layer-0 input gates (fp32 quads), 256 MB static
__device__ float4 g_gx4[(size_t)NB*TT*HH];

__global__ __launch_bounds__(256) void prep_kernel(
    const float* __restrict__ Wx0, const float* __restrict__ Wh0,
    const float* __restrict__ Wx1, const float* __restrict__ Wh1,
    const float* __restrict__ Wout)
{
  int i = blockIdx.x * 256 + threadIdx.x;   // grid covers 8192
  if (i < EE*HH) {
    int e = i / HH, u = i % HH;
    g_W4x0[i] = make_float4(Wx0[u*EE+e], Wx0[(u+HH)*EE+e],
                            Wx0[(u+2*HH)*EE+e], Wx0[(u+3*HH)*EE+e]);
  }
  if (i < NRP*HH) {
    int rp = i >> 7, u = i & 127;
    uint4 vh0, vx1, vh1;
    __half* p0 = (__half*)&vh0;
    __half* p1 = (__half*)&vx1;
    __half* p2 = (__half*)&vh1;
    #pragma unroll
    for (int g = 0; g < 4; ++g) {
      p0[g]   = __float2half(Wh0[(u+g*HH)*HH + 2*rp    ]);
      p0[4+g] = __float2half(Wh0[(u+g*HH)*HH + 2*rp + 1]);
      p1[g]   = __float2half(Wx1[(u+g*HH)*HH + 2*rp    ]);
      p1[4+g] = __float2half(Wx1[(u+g*HH)*HH + 2*rp + 1]);
      p2[g]   = __float2half(Wh1[(u+g*HH)*HH + 2*rp    ]);
      p2[4+g] = __float2half(Wh1[(u+g*HH)*HH + 2*rp + 1]);
    }
    g_h016[i] = vh0;
    g_x116[i] = vx1;
    g_h116[i] = vh1;
  }
  if (i < (HH/4)*VOUT) {
    int k4 = i / VOUT, v = i % VOUT;
    g_Wo4[i] = make_float4(Wout[v*HH+4*k4+0], Wout[v*HH+4*k4+1],
                           Wout[v*HH+4*k4+2], Wout[v*HH+4*k4+3]);
  }
}

__device__ __forceinline__ float sigf(float x) {
  return 1.0f / (1.0f + expf(-x));
}

__device__ __forceinline__ void gq_fma(float4& acc, float xs, float4 wq) {
  acc.x = fmaf(xs, wq.x, acc.x);
  acc.y = fmaf(xs, wq.y, acc.y);
  acc.z = fmaf(xs, wq.z, acc.z);
  acc.w = fmaf(xs, wq.w, acc.w);
}

// 2 k-rows x 4 gates from one 16B fp16 entry; fmaf(.., __half2float ..)
// lowers to v_fma_mix_f32 (fp32 fma with f16 operand, exact fp16->fp32).
__device__ __forceinline__ void rp_fma(float4& a, float2 hh, uint4 e) {
  const __half* eh = (const __half*)&e;
  a.x = fmaf(hh.x, __half2float(eh[0]), a.x);
  a.y = fmaf(hh.x, __half2float(eh[1]), a.y);
  a.z = fmaf(hh.x, __half2float(eh[2]), a.z);
  a.w = fmaf(hh.x, __half2float(eh[3]), a.w);
  a.x = fmaf(hh.y, __half2float(eh[4]), a.x);
  a.y = fmaf(hh.y, __half2float(eh[5]), a.y);
  a.z = fmaf(hh.y, __half2float(eh[6]), a.z);
  a.w = fmaf(hh.y, __half2float(eh[7]), a.w);
}

// ---------------------------------------------------------------------------
// Precompute g_gx4[b][t][u] = bx0_quad[u] + Wx0_quad . emb[src[b,t]]  (fp32)
// ---------------------------------------------------------------------------
__global__ __launch_bounds__(256) void xproj_kernel(
    const int*   __restrict__ src,  const int* __restrict__ lens,
    const float* __restrict__ emb,  const float* __restrict__ bx0)
{
  __shared__ float4 s_w[EE*HH];    // 128 KB
  __shared__ float4 s_x4[8][EE/4]; // 2 KB

  const int b    = blockIdx.x;
  const int tid  = threadIdx.x;
  const int u    = tid & 127;
  const int half = tid >> 7;

  for (int i = tid; i < EE*HH; i += 256) s_w[i] = g_W4x0[i];
  const int len = lens[b];
  const float4 bq = make_float4(bx0[u], bx0[u+HH], bx0[u+2*HH], bx0[u+3*HH]);
  const float4* __restrict__ emb4 = (const float4*)emb;
  __syncthreads();

  for (int t0 = 0; t0 < TT; t0 += 8) {
    if (t0 >= len) break;                       // block-uniform skip
    __syncthreads();
    if (tid < 128) {
      int p  = tid >> 4;
      int e4 = tid & 15;
      int tok = src[b*TT + t0 + p];
      s_x4[p][e4] = emb4[tok*(EE/4) + e4];
    }
    __syncthreads();

    float4 a0 = bq, a1 = bq, a2 = bq, a3 = bq;
    #pragma unroll
    for (int e4 = 0; e4 < EE/4; ++e4) {
      float4 w0 = s_w[(e4*4+0)*HH + u];
      float4 w1 = s_w[(e4*4+1)*HH + u];
      float4 w2 = s_w[(e4*4+2)*HH + u];
      float4 w3 = s_w[(e4*4+3)*HH + u];
      float4 x0 = s_x4[half*4+0][e4];
      float4 x1 = s_x4[half*4+1][e4];
      float4 x2 = s_x4[half*4+2][e4];
      float4 x3 = s_x4[half*4+3][e4];
      gq_fma(a0, x0.x, w0); gq_fma(a0, x0.y, w1); gq_fma(a0, x0.z, w2); gq_fma(a0, x0.w, w3);
      gq_fma(a1, x1.x, w0); gq_fma(a1, x1.y, w1); gq_fma(a1, x1.z, w2); gq_fma(a1, x1.w, w3);
      gq_fma(a2, x2.x, w0); gq_fma(a2, x2.y, w1); gq_fma(a2, x2.z, w2); gq_fma(a2, x2.w, w3);
      gq_fma(a3, x3.x, w0); gq_fma(a3, x3.y, w1); gq_fma(a3, x3.z, w2); gq_fma(a3, x3.w, w3);
    }
    size_t base = ((size_t)b*TT + t0 + half*4) * HH + u;
    g_gx4[base + 0*HH] = a0;
    g_gx4[base + 1*HH] = a1;
    g_gx4[base + 2*HH] = a2;
    g_gx4[base + 3*HH] = a3;
  }
}

// ---------------------------------------------------------------------------
// Recurrent kernel: thread = (r,u,kh). Each lane covers row-pairs rp=2j+kh
// (64 of 128 k-rows); pair lanes (2u,2u+1) combine via one __shfl_xor per
// gate. Wh0 is FULLY LDS-resident (fp16, 131 KB) -> layer0 has zero global
// weight traffic; layer1 streams Wx1+Wh1 fp16 (262 KB/block-step, L2-hot).
// Writes h1 into d_out; proj_kernel converts to logits in-place.
// ---------------------------------------------------------------------------
__global__ __launch_bounds__(NTHR) void lstm_kernel(
    const int*   __restrict__ lens,
    const float* __restrict__ bx1,
    float*       __restrict__ out)
{
  __shared__ uint4 s_wh016[NRP*HH];    // 131 KB: all of Wh0 (fp16 row-pairs)
  __shared__ float s_h0[2][RPB][HH];   // 2 KB ping-pong
  __shared__ float s_h1[2][RPB][HH];   // 2 KB
  __shared__ float s_bx1[G4];          // 2 KB
  __shared__ int   s_len[RPB];

  const int tid = threadIdx.x;
  const int r   = tid >> 8;        // 0/1, wave-uniform (waves 0-3 / 4-7)
  const int u   = (tid >> 1) & 127;
  const int kh  = tid & 1;
  const int row = blockIdx.x * RPB;

  for (int i = tid; i < NRP*HH; i += NTHR) s_wh016[i] = g_h016[i];
  for (int i = tid; i < G4;     i += NTHR) s_bx1[i]  = bx1[i];
  if (tid < RPB) s_len[tid] = lens[row + tid];
  if (tid < RPB*HH) {
    int rr = tid >> 7, uu = tid & 127;
    s_h0[0][rr][uu] = 0.0f; s_h0[1][rr][uu] = 0.0f;
    s_h1[0][rr][uu] = 0.0f; s_h1[1][rr][uu] = 0.0f;
  }
  __syncthreads();

  const int len_r  = s_len[r];
  const int maxlen = max(s_len[0], s_len[1]);
  float c0 = 0.0f, c1 = 0.0f;      // redundant in both kh lanes (identical)
  float h1keep = 0.0f;
  float* outrow = out + (size_t)(row + r) * TT * HH;

  const float4 b1q = make_float4(s_bx1[u], s_bx1[u+HH], s_bx1[u+2*HH], s_bx1[u+3*HH]);
  // entry pointers offset by this lane's kh: index stride j*(2*HH)
  const uint4* __restrict__ wh0p = s_wh016 + kh*HH + u;
  const uint4* __restrict__ wx1p = g_x116  + kh*HH + u;
  const uint4* __restrict__ wh1p = g_h116  + kh*HH + u;
  const float4* __restrict__ gxr = g_gx4 + (size_t)(row + r) * TT * HH + u;

  for (int t = 0; t < maxlen; ++t) {
    const int  pp  = t & 1;        // read buffer; write to pp^1
    const bool act = (t < len_r);  // wave-uniform

    // ---------- layer 0: Wh0 entirely from LDS ----------
    if (act) {
      float4 a = make_float4(0.0f, 0.0f, 0.0f, 0.0f);
      const float* hb = &s_h0[pp][r][2*kh];        // hb[4j] = h rows 4j+2kh..+1
      #pragma unroll 8
      for (int j = 0; j < 32; ++j) {
        float2 hh = *(const float2*)(hb + 4*j);
        rp_fma(a, hh, wh0p[j*(2*HH)]);
      }
      a.x += __shfl_xor(a.x, 1); a.y += __shfl_xor(a.y, 1);
      a.z += __shfl_xor(a.z, 1); a.w += __shfl_xor(a.w, 1);
      float4 gq4 = gxr[(size_t)t * HH];            // bx0 + Wx0.x_t (fp32)
      a.x += gq4.x; a.y += gq4.y; a.z += gq4.z; a.w += gq4.w;
      float i_ = sigf(a.x), f_ = sigf(a.y), g_ = tanhf(a.z), o_ = sigf(a.w);
      c0 = fmaf(f_, c0, i_ * g_);
      float h0n = o_ * tanhf(c0);
      if (kh == 0) s_h0[pp^1][r][u] = h0n;
    }
    __syncthreads();               // new h0 visible

    // ---------- layer 1: Wx1 + Wh1 streamed (fp16) ----------
    if (act) {
      float4 a = make_float4(0.0f, 0.0f, 0.0f, 0.0f);
      const float* xb = &s_h0[pp^1][r][2*kh];
      #pragma unroll 8
      for (int j = 0; j < 32; ++j) {
        float2 xx = *(const float2*)(xb + 4*j);
        rp_fma(a, xx, wx1p[j*(2*HH)]);
      }
      const float* hb = &s_h1[pp][r][2*kh];
      #pragma unroll 8
      for (int j = 0; j < 32; ++j) {
        float2 hh = *(const float2*)(hb + 4*j);
        rp_fma(a, hh, wh1p[j*(2*HH)]);
      }
      a.x += __shfl_xor(a.x, 1); a.y += __shfl_xor(a.y, 1);
      a.z += __shfl_xor(a.z, 1); a.w += __shfl_xor(a.w, 1);
      a.x += b1q.x; a.y += b1q.y; a.z += b1q.z; a.w += b1q.w;
      float i_ = sigf(a.x), f_ = sigf(a.y), g_ = tanhf(a.z), o_ = sigf(a.w);
      c1 = fmaf(f_, c1, i_ * g_);
      float h1n = o_ * tanhf(c1);
      if (kh == 0) s_h1[pp^1][r][u] = h1n;
      h1keep = h1n;
    }
    if (kh == 0) outrow[(size_t)t * HH + u] = h1keep;  // frozen when inactive
    __syncthreads();               // new h1 visible
  }

  // barrier-free tail: h1 frozen for t >= maxlen
  for (int t = maxlen; t < TT; ++t)
    if (kh == 0) outrow[(size_t)t * HH + u] = h1keep;
}

// ---------------------------------------------------------------------------
// In-place projection: d_out rows h1 -> logits (fp32).
// ---------------------------------------------------------------------------
__global__ __launch_bounds__(256) void proj_kernel(
    const float* __restrict__ bout, float* __restrict__ out)
{
  __shared__ float4 s_wo[(HH/4)*VOUT];   // 64 KB
  __shared__ float  s_bout[VOUT];

  const int tid  = threadIdx.x;
  const int wid  = tid >> 6;
  const int lane = tid & 63;

  for (int i = tid; i < (HH/4)*VOUT; i += 256) s_wo[i] = g_Wo4[i];
  if (tid < VOUT) s_bout[tid] = bout[tid];
  __syncthreads();

  const int PPB = (NB*TT) / 256;         // 512 rows per block
  const int start = blockIdx.x * PPB;
  for (int it = 0; it < PPB/4; ++it) {
    const int pair = start + it*4 + wid;
    float* rowp = out + (size_t)pair * HH;
    float v0 = s_bout[lane], v1 = s_bout[lane + 64];
    #pragma unroll 8
    for (int k4 = 0; k4 < HH/4; ++k4) {
      float4 h4 = *(const float4*)(rowp + k4*4);   // wave-uniform broadcast
      float4 w0 = s_wo[k4*VOUT + lane];
      float4 w1 = s_wo[k4*VOUT + lane + 64];
      v0 = fmaf(h4.x,w0.x, fmaf(h4.y,w0.y, fmaf(h4.z,w0.z, fmaf(h4.w,w0.w, v0))));
      v1 = fmaf(h4.x,w1.x, fmaf(h4.y,w1.y, fmaf(h4.z,w1.z, fmaf(h4.w,w1.w, v1))));
    }
    rowp[lane]      = v0;
    rowp[lane + 64] = v1;
  }
}

extern "C" void kernel_launch(void* const* d_in, const int* in_sizes, int n_in,
                              void* d_out, int out_size, void* d_ws, size_t ws_size,
                              hipStream_t stream) {
  const int*   src  = (const int*)  d_in[0];
  const int*   lens = (const int*)  d_in[1];
  const float* emb  = (const float*)d_in[2];
  const float* Wx0  = (const float*)d_in[3];
  const float* bx0  = (const float*)d_in[4];
  const float* Wh0  = (const float*)d_in[5];
  const float* Wx1  = (const float*)d_in[6];
  const float* bx1  = (const float*)d_in[7];
  const float* Wh1  = (const float*)d_in[8];
  const float* Wout = (const float*)d_in[9];
  const float* bout = (const float*)d_in[10];
  float* out = (float*)d_out;

  hipLaunchKernelGGL(prep_kernel, dim3(32), dim3(256), 0, stream,
                     Wx0, Wh0, Wx1, Wh1, Wout);
  hipLaunchKernelGGL(xproj_kernel, dim3(NB), dim3(256), 0, stream,
                     src, lens, emb, bx0);
  hipLaunchKernelGGL(lstm_kernel, dim3(NWG), dim3(NTHR), 0, stream,
                     lens, bx1, out);
  hipLaunchKernelGGL(proj_kernel, dim3(256), dim3(256), 0, stream,
                     bout, out);
}

// Round 10
// 3516.669 us; speedup vs baseline: 1.6495x; 1.5987x over previous
//
#include <hip/hip_runtime.h>
#include <hip/hip_fp16.h>
#include <math.h>

#define NB   256   // batch
#define TT   512   // seq len
#define EE   64
#define HH   128
#define G4   (4*HH)
#define VOUT 128
#define NTHR 512      // threads: (u,kq) = 128 x 4
#define NE   (16*128*4)  // 8192 row-pair entries per matrix

// fp32 packs for the parallel kernels
__device__ float4 g_W4x0[EE*HH];        // [e][u] gate quads, 128 KB
__device__ float4 g_Wo4[(HH/4)*VOUT];   // [k4][v], 64 KB
// fp16 row-pair packs, layout [j][u][kq] (idx = j*512 + u*4 + kq).
// Entry (j,u,kq) = 16 B = { quad(k0,u), quad(k0+1,u) }, k0 = 32*kq + 2*j,
// quad = {W[u][k], W[u+H][k], W[u+2H][k], W[u+3H][k]}
__device__ uint4  g_h016[NE];           // Wh0, 131 KB
__device__ uint4  g_x116[NE];           // Wx1, 131 KB
__device__ uint4  g_h116[NE];           // Wh1, 131 KB
// Precomputed layer-0 input gates (fp32 quads), 256 MB static
__device__ float4 g_gx4[(size_t)NB*TT*HH];

__global__ __launch_bounds__(256) void prep_kernel(
    const float* __restrict__ Wx0, const float* __restrict__ Wh0,
    const float* __restrict__ Wx1, const float* __restrict__ Wh1,
    const float* __restrict__ Wout)
{
  int i = blockIdx.x * 256 + threadIdx.x;   // grid covers 8192
  if (i < EE*HH) {
    int e = i / HH, u = i % HH;
    g_W4x0[i] = make_float4(Wx0[u*EE+e], Wx0[(u+HH)*EE+e],
                            Wx0[(u+2*HH)*EE+e], Wx0[(u+3*HH)*EE+e]);
  }
  if (i < NE) {
    int kq = i & 3, u = (i >> 2) & 127, j = i >> 9;
    int k0 = 32*kq + 2*j;
    uint4 vh0, vx1, vh1;
    __half* p0 = (__half*)&vh0;
    __half* p1 = (__half*)&vx1;
    __half* p2 = (__half*)&vh1;
    #pragma unroll
    for (int g = 0; g < 4; ++g) {
      p0[g]   = __float2half(Wh0[(u+g*HH)*HH + k0    ]);
      p0[4+g] = __float2half(Wh0[(u+g*HH)*HH + k0 + 1]);
      p1[g]   = __float2half(Wx1[(u+g*HH)*HH + k0    ]);
      p1[4+g] = __float2half(Wx1[(u+g*HH)*HH + k0 + 1]);
      p2[g]   = __float2half(Wh1[(u+g*HH)*HH + k0    ]);
      p2[4+g] = __float2half(Wh1[(u+g*HH)*HH + k0 + 1]);
    }
    g_h016[i] = vh0;
    g_x116[i] = vx1;
    g_h116[i] = vh1;
  }
  if (i < (HH/4)*VOUT) {
    int k4 = i / VOUT, v = i % VOUT;
    g_Wo4[i] = make_float4(Wout[v*HH+4*k4+0], Wout[v*HH+4*k4+1],
                           Wout[v*HH+4*k4+2], Wout[v*HH+4*k4+3]);
  }
}

__device__ __forceinline__ float sigf(float x) {
  return 1.0f / (1.0f + expf(-x));
}

__device__ __forceinline__ void gq_fma(float4& acc, float xs, float4 wq) {
  acc.x = fmaf(xs, wq.x, acc.x);
  acc.y = fmaf(xs, wq.y, acc.y);
  acc.z = fmaf(xs, wq.z, acc.z);
  acc.w = fmaf(xs, wq.w, acc.w);
}

// 2 k-rows x 4 gates from one 16B fp16 entry; lowers to v_fma_mix_f32.
__device__ __forceinline__ void rp_fma(float4& a, float2 hh, uint4 e) {
  const __half* eh = (const __half*)&e;
  a.x = fmaf(hh.x, __half2float(eh[0]), a.x);
  a.y = fmaf(hh.x, __half2float(eh[1]), a.y);
  a.z = fmaf(hh.x, __half2float(eh[2]), a.z);
  a.w = fmaf(hh.x, __half2float(eh[3]), a.w);
  a.x = fmaf(hh.y, __half2float(eh[4]), a.x);
  a.y = fmaf(hh.y, __half2float(eh[5]), a.y);
  a.z = fmaf(hh.y, __half2float(eh[6]), a.z);
  a.w = fmaf(hh.y, __half2float(eh[7]), a.w);
}

// ---------------------------------------------------------------------------
// Precompute g_gx4[b][t][u] = bx0_quad[u] + Wx0_quad . emb[src[b,t]]  (fp32)
// ---------------------------------------------------------------------------
__global__ __launch_bounds__(256) void xproj_kernel(
    const int*   __restrict__ src,  const int* __restrict__ lens,
    const float* __restrict__ emb,  const float* __restrict__ bx0)
{
  __shared__ float4 s_w[EE*HH];    // 128 KB
  __shared__ float4 s_x4[8][EE/4]; // 2 KB

  const int b    = blockIdx.x;
  const int tid  = threadIdx.x;
  const int u    = tid & 127;
  const int half = tid >> 7;

  for (int i = tid; i < EE*HH; i += 256) s_w[i] = g_W4x0[i];
  const int len = lens[b];
  const float4 bq = make_float4(bx0[u], bx0[u+HH], bx0[u+2*HH], bx0[u+3*HH]);
  const float4* __restrict__ emb4 = (const float4*)emb;
  __syncthreads();

  for (int t0 = 0; t0 < TT; t0 += 8) {
    if (t0 >= len) break;                       // block-uniform skip
    __syncthreads();
    if (tid < 128) {
      int p  = tid >> 4;
      int e4 = tid & 15;
      int tok = src[b*TT + t0 + p];
      s_x4[p][e4] = emb4[tok*(EE/4) + e4];
    }
    __syncthreads();

    float4 a0 = bq, a1 = bq, a2 = bq, a3 = bq;
    #pragma unroll
    for (int e4 = 0; e4 < EE/4; ++e4) {
      float4 w0 = s_w[(e4*4+0)*HH + u];
      float4 w1 = s_w[(e4*4+1)*HH + u];
      float4 w2 = s_w[(e4*4+2)*HH + u];
      float4 w3 = s_w[(e4*4+3)*HH + u];
      float4 x0 = s_x4[half*4+0][e4];
      float4 x1 = s_x4[half*4+1][e4];
      float4 x2 = s_x4[half*4+2][e4];
      float4 x3 = s_x4[half*4+3][e4];
      gq_fma(a0, x0.x, w0); gq_fma(a0, x0.y, w1); gq_fma(a0, x0.z, w2); gq_fma(a0, x0.w, w3);
      gq_fma(a1, x1.x, w0); gq_fma(a1, x1.y, w1); gq_fma(a1, x1.z, w2); gq_fma(a1, x1.w, w3);
      gq_fma(a2, x2.x, w0); gq_fma(a2, x2.y, w1); gq_fma(a2, x2.z, w2); gq_fma(a2, x2.w, w3);
      gq_fma(a3, x3.x, w0); gq_fma(a3, x3.y, w1); gq_fma(a3, x3.z, w2); gq_fma(a3, x3.w, w3);
    }
    size_t base = ((size_t)b*TT + t0 + half*4) * HH + u;
    g_gx4[base + 0*HH] = a0;
    g_gx4[base + 1*HH] = a1;
    g_gx4[base + 2*HH] = a2;
    g_gx4[base + 3*HH] = a3;
  }
}

// ---------------------------------------------------------------------------
// Recurrent kernel: ONE batch row per block, 512 threads = (u,kq) = 128x4.
// Thread (u,kq) owns k-rows {32kq+2j, 32kq+2j+1}, j=0..15 for all matrices.
// Wx1+Wh1 are REGISTER-RESIDENT (32 uint4 fp16, loaded once) -> layer 1 does
// zero memory traffic per step. Wh0 is LDS-resident, layout [j][u][kq] ->
// lane-sequential 16B reads, conflict-free. kq-partials combine via 2
// __shfl_xor levels. h buffers skewed by 34*kq to avoid 128B-stride banks.
// Writes h1 into d_out; proj_kernel converts to logits in-place.
// ---------------------------------------------------------------------------
__global__ __launch_bounds__(NTHR) void lstm_kernel(
    const int*   __restrict__ lens,
    const float* __restrict__ bx1,
    float*       __restrict__ out)
{
  __shared__ uint4 s_w0[NE];                     // 131 KB: all of Wh0
  __shared__ __align__(16) float s_h0[2][136];   // skewed: u at [u + 2*(u>>5)]
  __shared__ __align__(16) float s_h1[2][136];

  const int tid = threadIdx.x;
  const int u   = tid >> 2;
  const int kq  = tid & 3;
  const int b   = blockIdx.x;

  for (int i = tid; i < NE; i += NTHR) s_w0[i] = g_h016[i];

  // layer-1 weights -> registers (32 uint4 = 128 VGPR), statically indexed
  uint4 wx_[16], wh_[16];
  #pragma unroll
  for (int j = 0; j < 16; ++j) {
    wx_[j] = g_x116[j*512 + tid];
    wh_[j] = g_h116[j*512 + tid];
  }
  const float4 b1q = make_float4(bx1[u], bx1[u+HH], bx1[u+2*HH], bx1[u+3*HH]);
  if (tid < 256) {
    int p = tid >> 7, x = tid & 127;
    s_h0[p][x + 2*(x>>5)] = 0.0f;
    s_h1[p][x + 2*(x>>5)] = 0.0f;
  }
  const int len = lens[b];
  __syncthreads();

  float c0 = 0.0f, c1 = 0.0f;          // redundant across kq (identical)
  float h1keep = 0.0f;
  float* outrow = out + (size_t)b * TT * HH;
  const float4* __restrict__ gxr = g_gx4 + (size_t)b * TT * HH + u;
  const uint4*  __restrict__ w0p = s_w0 + tid;     // [j*512 + tid]
  const int hbase = 34*kq;             // skewed base of this kq's h quarter

  for (int t = 0; t < len; ++t) {
    const int pp = t & 1;

    // issue the precomputed x-gate load FIRST: its ~300cy latency hides
    // under the 16-deep LDS FMA chain below (no dependence on s_h0)
    float4 g4 = gxr[(size_t)t * HH];   // bx0 + Wx0.x_t (fp32)

    // ---------- layer 0: Wh0 from LDS ----------
    {
      float4 a = make_float4(0.0f, 0.0f, 0.0f, 0.0f);
      #pragma unroll
      for (int j = 0; j < 16; ++j) {
        float2 hh = *(const float2*)(&s_h0[pp][hbase + 2*j]);
        rp_fma(a, hh, w0p[j*512]);
      }
      a.x += __shfl_xor(a.x, 1); a.y += __shfl_xor(a.y, 1);
      a.z += __shfl_xor(a.z, 1); a.w += __shfl_xor(a.w, 1);
      a.x += __shfl_xor(a.x, 2); a.y += __shfl_xor(a.y, 2);
      a.z += __shfl_xor(a.z, 2); a.w += __shfl_xor(a.w, 2);
      a.x += g4.x; a.y += g4.y; a.z += g4.z; a.w += g4.w;
      float i_ = sigf(a.x), f_ = sigf(a.y), g_ = tanhf(a.z), o_ = sigf(a.w);
      c0 = fmaf(f_, c0, i_ * g_);
      float h0n = o_ * tanhf(c0);
      if (kq == 0) s_h0[pp^1][u + 2*(u>>5)] = h0n;
    }
    __syncthreads();                   // new h0 visible

    // ---------- layer 1: weights from REGISTERS ----------
    {
      float4 a = make_float4(0.0f, 0.0f, 0.0f, 0.0f);
      #pragma unroll
      for (int j = 0; j < 16; ++j) {
        float2 xx = *(const float2*)(&s_h0[pp^1][hbase + 2*j]);
        rp_fma(a, xx, wx_[j]);
      }
      #pragma unroll
      for (int j = 0; j < 16; ++j) {
        float2 hh = *(const float2*)(&s_h1[pp][hbase + 2*j]);
        rp_fma(a, hh, wh_[j]);
      }
      a.x += __shfl_xor(a.x, 1); a.y += __shfl_xor(a.y, 1);
      a.z += __shfl_xor(a.z, 1); a.w += __shfl_xor(a.w, 1);
      a.x += __shfl_xor(a.x, 2); a.y += __shfl_xor(a.y, 2);
      a.z += __shfl_xor(a.z, 2); a.w += __shfl_xor(a.w, 2);
      a.x += b1q.x; a.y += b1q.y; a.z += b1q.z; a.w += b1q.w;
      float i_ = sigf(a.x), f_ = sigf(a.y), g_ = tanhf(a.z), o_ = sigf(a.w);
      c1 = fmaf(f_, c1, i_ * g_);
      float h1n = o_ * tanhf(c1);
      if (kq == 0) {
        s_h1[pp^1][u + 2*(u>>5)] = h1n;
        outrow[(size_t)t * HH + u] = h1n;
      }
      h1keep = h1n;
    }
    __syncthreads();                   // new h1 visible
  }

  // tail: h1 frozen for t >= len; parallel over kq
  for (int t = len + kq; t < TT; t += 4)
    outrow[(size_t)t * HH + u] = h1keep;
}

// ---------------------------------------------------------------------------
// In-place projection: d_out rows h1 -> logits (fp32).
// ---------------------------------------------------------------------------
__global__ __launch_bounds__(256) void proj_kernel(
    const float* __restrict__ bout, float* __restrict__ out)
{
  __shared__ float4 s_wo[(HH/4)*VOUT];   // 64 KB
  __shared__ float  s_bout[VOUT];

  const int tid  = threadIdx.x;
  const int wid  = tid >> 6;
  const int lane = tid & 63;

  for (int i = tid; i < (HH/4)*VOUT; i += 256) s_wo[i] = g_Wo4[i];
  if (tid < VOUT) s_bout[tid] = bout[tid];
  __syncthreads();

  const int PPB = (NB*TT) / 256;         // 512 rows per block
  const int start = blockIdx.x * PPB;
  for (int it = 0; it < PPB/4; ++it) {
    const int pair = start + it*4 + wid;
    float* rowp = out + (size_t)pair * HH;
    float v0 = s_bout[lane], v1 = s_bout[lane + 64];
    #pragma unroll 8
    for (int k4 = 0; k4 < HH/4; ++k4) {
      float4 h4 = *(const float4*)(rowp + k4*4);   // wave-uniform broadcast
      float4 w0 = s_wo[k4*VOUT + lane];
      float4 w1 = s_wo[k4*VOUT + lane + 64];
      v0 = fmaf(h4.x,w0.x, fmaf(h4.y,w0.y, fmaf(h4.z,w0.z, fmaf(h4.w,w0.w, v0))));
      v1 = fmaf(h4.x,w1.x, fmaf(h4.y,w1.y, fmaf(h4.z,w1.z, fmaf(h4.w,w1.w, v1))));
    }
    rowp[lane]      = v0;
    rowp[lane + 64] = v1;
  }
}

extern "C" void kernel_launch(void* const* d_in, const int* in_sizes, int n_in,
                              void* d_out, int out_size, void* d_ws, size_t ws_size,
                              hipStream_t stream) {
  const int*   src  = (const int*)  d_in[0];
  const int*   lens = (const int*)  d_in[1];
  const float* emb  = (const float*)d_in[2];
  const float* Wx0  = (const float*)d_in[3];
  const float* bx0  = (const float*)d_in[4];
  const float* Wh0  = (const float*)d_in[5];
  const float* Wx1  = (const float*)d_in[6];
  const float* bx1  = (const float*)d_in[7];
  const float* Wh1  = (const float*)d_in[8];
  const float* Wout = (const float*)d_in[9];
  const float* bout = (const float*)d_in[10];
  float* out = (float*)d_out;

  hipLaunchKernelGGL(prep_kernel, dim3(32), dim3(256), 0, stream,
                     Wx0, Wh0, Wx1, Wh1, Wout);
  hipLaunchKernelGGL(xproj_kernel, dim3(NB), dim3(256), 0, stream,
                     src, lens, emb, bx0);
  hipLaunchKernelGGL(lstm_kernel, dim3(NB), dim3(NTHR), 0, stream,
                     lens, bx1, out);
  hipLaunchKernelGGL(proj_kernel, dim3(256), dim3(256), 0, stream,
                     bout, out);
}

// Round 12
// 3511.958 us; speedup vs baseline: 1.6517x; 1.0013x over previous
//
#include <hip/hip_runtime.h>
#include <hip/hip_fp16.h>
#include <math.h>

#define NB   256   // batch
#define TT   512   // seq len
#define EE   64
#define HH   128
#define G4   (4*HH)
#define VOUT 128
#define NTHR 512      // threads: (u,kq) = 128 x 4
#define NE   (16*128*4)  // 8192 row-pair entries per matrix

// fp32 packs for the parallel kernels
__device__ float4 g_W4x0[EE*HH];        // [e][u] gate quads, 128 KB
__device__ float4 g_Wo4[(HH/4)*VOUT];   // [k4][v], 64 KB
// fp16 row-pair packs, layout [j][u][kq] (idx = j*512 + u*4 + kq).
// Entry (j,u,kq) = 16 B = { quad(k0,u), quad(k0+1,u) }, k0 = 32*kq + 2*j,
// quad = {W[u][k], W[u+H][k], W[u+2H][k], W[u+3H][k]}
__device__ uint4  g_h016[NE];           // Wh0, 131 KB
__device__ uint4  g_x116[NE];           // Wx1, 131 KB
__device__ uint4  g_h116[NE];           // Wh1, 131 KB
// Precomputed layer-0 input gates (fp32 quads), 256 MB static
__device__ float4 g_gx4[(size_t)NB*TT*HH];

__global__ __launch_bounds__(256) void prep_kernel(
    const float* __restrict__ Wx0, const float* __restrict__ Wh0,
    const float* __restrict__ Wx1, const float* __restrict__ Wh1,
    const float* __restrict__ Wout)
{
  int i = blockIdx.x * 256 + threadIdx.x;   // grid covers 8192
  if (i < EE*HH) {
    int e = i / HH, u = i % HH;
    g_W4x0[i] = make_float4(Wx0[u*EE+e], Wx0[(u+HH)*EE+e],
                            Wx0[(u+2*HH)*EE+e], Wx0[(u+3*HH)*EE+e]);
  }
  if (i < NE) {
    int kq = i & 3, u = (i >> 2) & 127, j = i >> 9;
    int k0 = 32*kq + 2*j;
    uint4 vh0, vx1, vh1;
    __half* p0 = (__half*)&vh0;
    __half* p1 = (__half*)&vx1;
    __half* p2 = (__half*)&vh1;
    #pragma unroll
    for (int g = 0; g < 4; ++g) {
      p0[g]   = __float2half(Wh0[(u+g*HH)*HH + k0    ]);
      p0[4+g] = __float2half(Wh0[(u+g*HH)*HH + k0 + 1]);
      p1[g]   = __float2half(Wx1[(u+g*HH)*HH + k0    ]);
      p1[4+g] = __float2half(Wx1[(u+g*HH)*HH + k0 + 1]);
      p2[g]   = __float2half(Wh1[(u+g*HH)*HH + k0    ]);
      p2[4+g] = __float2half(Wh1[(u+g*HH)*HH + k0 + 1]);
    }
    g_h016[i] = vh0;
    g_x116[i] = vx1;
    g_h116[i] = vh1;
  }
  if (i < (HH/4)*VOUT) {
    int k4 = i / VOUT, v = i % VOUT;
    g_Wo4[i] = make_float4(Wout[v*HH+4*k4+0], Wout[v*HH+4*k4+1],
                           Wout[v*HH+4*k4+2], Wout[v*HH+4*k4+3]);
  }
}

__device__ __forceinline__ float sigf(float x) {
  return 1.0f / (1.0f + expf(-x));
}

__device__ __forceinline__ void gq_fma(float4& acc, float xs, float4 wq) {
  acc.x = fmaf(xs, wq.x, acc.x);
  acc.y = fmaf(xs, wq.y, acc.y);
  acc.z = fmaf(xs, wq.z, acc.z);
  acc.w = fmaf(xs, wq.w, acc.w);
}

// 2 k-rows x 4 gates from one 16B fp16 entry; lowers to v_fma_mix_f32.
__device__ __forceinline__ void rp_fma(float4& a, float2 hh, uint4 e) {
  const __half* eh = (const __half*)&e;
  a.x = fmaf(hh.x, __half2float(eh[0]), a.x);
  a.y = fmaf(hh.x, __half2float(eh[1]), a.y);
  a.z = fmaf(hh.x, __half2float(eh[2]), a.z);
  a.w = fmaf(hh.x, __half2float(eh[3]), a.w);
  a.x = fmaf(hh.y, __half2float(eh[4]), a.x);
  a.y = fmaf(hh.y, __half2float(eh[5]), a.y);
  a.z = fmaf(hh.y, __half2float(eh[6]), a.z);
  a.w = fmaf(hh.y, __half2float(eh[7]), a.w);
}

// ---------------------------------------------------------------------------
// Precompute g_gx4[b][t][u] = bx0_quad[u] + Wx0_quad . emb[src[b,t]]  (fp32)
// ---------------------------------------------------------------------------
__global__ __launch_bounds__(256) void xproj_kernel(
    const int*   __restrict__ src,  const int* __restrict__ lens,
    const float* __restrict__ emb,  const float* __restrict__ bx0)
{
  __shared__ float4 s_w[EE*HH];    // 128 KB
  __shared__ float4 s_x4[8][EE/4]; // 2 KB

  const int b    = blockIdx.x;
  const int tid  = threadIdx.x;
  const int u    = tid & 127;
  const int half = tid >> 7;

  for (int i = tid; i < EE*HH; i += 256) s_w[i] = g_W4x0[i];
  const int len = lens[b];
  const float4 bq = make_float4(bx0[u], bx0[u+HH], bx0[u+2*HH], bx0[u+3*HH]);
  const float4* __restrict__ emb4 = (const float4*)emb;
  __syncthreads();

  for (int t0 = 0; t0 < TT; t0 += 8) {
    if (t0 >= len) break;                       // block-uniform skip
    __syncthreads();
    if (tid < 128) {
      int p  = tid >> 4;
      int e4 = tid & 15;
      int tok = src[b*TT + t0 + p];
      s_x4[p][e4] = emb4[tok*(EE/4) + e4];
    }
    __syncthreads();

    float4 a0 = bq, a1 = bq, a2 = bq, a3 = bq;
    #pragma unroll
    for (int e4 = 0; e4 < EE/4; ++e4) {
      float4 w0 = s_w[(e4*4+0)*HH + u];
      float4 w1 = s_w[(e4*4+1)*HH + u];
      float4 w2 = s_w[(e4*4+2)*HH + u];
      float4 w3 = s_w[(e4*4+3)*HH + u];
      float4 x0 = s_x4[half*4+0][e4];
      float4 x1 = s_x4[half*4+1][e4];
      float4 x2 = s_x4[half*4+2][e4];
      float4 x3 = s_x4[half*4+3][e4];
      gq_fma(a0, x0.x, w0); gq_fma(a0, x0.y, w1); gq_fma(a0, x0.z, w2); gq_fma(a0, x0.w, w3);
      gq_fma(a1, x1.x, w0); gq_fma(a1, x1.y, w1); gq_fma(a1, x1.z, w2); gq_fma(a1, x1.w, w3);
      gq_fma(a2, x2.x, w0); gq_fma(a2, x2.y, w1); gq_fma(a2, x2.z, w2); gq_fma(a2, x2.w, w3);
      gq_fma(a3, x3.x, w0); gq_fma(a3, x3.y, w1); gq_fma(a3, x3.z, w2); gq_fma(a3, x3.w, w3);
    }
    size_t base = ((size_t)b*TT + t0 + half*4) * HH + u;
    g_gx4[base + 0*HH] = a0;
    g_gx4[base + 1*HH] = a1;
    g_gx4[base + 2*HH] = a2;
    g_gx4[base + 3*HH] = a3;
  }
}

// ---------------------------------------------------------------------------
// Recurrent kernel: ONE batch row per block, 512 threads = (u,kq) = 128x4.
// Thread (u,kq) owns k-rows {32kq+2j, 32kq+2j+1}, j=0..15 for all matrices.
// Wx1+Wh1 are REGISTER-RESIDENT (32 uint4 = 128 VGPR), so the kernel NEEDS
// ~200 VGPRs: __launch_bounds__(512, 2) = 2 waves/EU minimum (exactly our
// 8 waves / 4 SIMDs) raises the allocator cap to 256 VGPR. Round-10's
// default heuristic capped at 128 and SPILLED the weight file to scratch
// (VGPR_Count=128 with a 128-VGPR live array is the smoking gun).
// Wh0 is LDS-resident, layout [j][u][kq] -> lane-sequential 16B reads,
// conflict-free (round-10: SQ_LDS_BANK_CONFLICT = 0 confirmed).
// ---------------------------------------------------------------------------
__global__ __launch_bounds__(NTHR, 2) void lstm_kernel(
    const int*   __restrict__ lens,
    const float* __restrict__ bx1,
    float*       __restrict__ out)
{
  __shared__ uint4 s_w0[NE];                     // 131 KB: all of Wh0
  __shared__ __align__(16) float s_h0[2][136];   // skewed: u at [u + 2*(u>>5)]
  __shared__ __align__(16) float s_h1[2][136];

  const int tid = threadIdx.x;
  const int u   = tid >> 2;
  const int kq  = tid & 3;
  const int b   = blockIdx.x;

  for (int i = tid; i < NE; i += NTHR) s_w0[i] = g_h016[i];

  // layer-1 weights -> registers (32 uint4 = 128 VGPR), statically indexed
  uint4 wx_[16], wh_[16];
  #pragma unroll
  for (int j = 0; j < 16; ++j) {
    wx_[j] = g_x116[j*512 + tid];
    wh_[j] = g_h116[j*512 + tid];
  }
  const float4 b1q = make_float4(bx1[u], bx1[u+HH], bx1[u+2*HH], bx1[u+3*HH]);
  if (tid < 256) {
    int p = tid >> 7, x = tid & 127;
    s_h0[p][x + 2*(x>>5)] = 0.0f;
    s_h1[p][x + 2*(x>>5)] = 0.0f;
  }
  const int len = lens[b];
  __syncthreads();

  float c0 = 0.0f, c1 = 0.0f;          // redundant across kq (identical)
  float h1keep = 0.0f;
  float* outrow = out + (size_t)b * TT * HH;
  const float4* __restrict__ gxr = g_gx4 + (size_t)b * TT * HH + u;
  const uint4*  __restrict__ w0p = s_w0 + tid;     // [j*512 + tid]
  const int hbase = 34*kq;             // skewed base of this kq's h quarter

  for (int t = 0; t < len; ++t) {
    const int pp = t & 1;

    // issue the precomputed x-gate load FIRST: its latency hides under the
    // 16-deep LDS FMA chain below (no dependence on s_h0)
    float4 g4 = gxr[(size_t)t * HH];   // bx0 + Wx0.x_t (fp32)

    // ---------- layer 0: Wh0 from LDS ----------
    {
      float4 a = make_float4(0.0f, 0.0f, 0.0f, 0.0f);
      #pragma unroll
      for (int j = 0; j < 16; ++j) {
        float2 hh = *(const float2*)(&s_h0[pp][hbase + 2*j]);
        rp_fma(a, hh, w0p[j*512]);
      }
      a.x += __shfl_xor(a.x, 1); a.y += __shfl_xor(a.y, 1);
      a.z += __shfl_xor(a.z, 1); a.w += __shfl_xor(a.w, 1);
      a.x += __shfl_xor(a.x, 2); a.y += __shfl_xor(a.y, 2);
      a.z += __shfl_xor(a.z, 2); a.w += __shfl_xor(a.w, 2);
      a.x += g4.x; a.y += g4.y; a.z += g4.z; a.w += g4.w;
      float i_ = sigf(a.x), f_ = sigf(a.y), g_ = tanhf(a.z), o_ = sigf(a.w);
      c0 = fmaf(f_, c0, i_ * g_);
      float h0n = o_ * tanhf(c0);
      if (kq == 0) s_h0[pp^1][u + 2*(u>>5)] = h0n;
    }
    __syncthreads();                   // new h0 visible

    // ---------- layer 1: weights from REGISTERS ----------
    {
      float4 a = make_float4(0.0f, 0.0f, 0.0f, 0.0f);
      #pragma unroll
      for (int j = 0; j < 16; ++j) {
        float2 xx = *(const float2*)(&s_h0[pp^1][hbase + 2*j]);
        rp_fma(a, xx, wx_[j]);
      }
      #pragma unroll
      for (int j = 0; j < 16; ++j) {
        float2 hh = *(const float2*)(&s_h1[pp][hbase + 2*j]);
        rp_fma(a, hh, wh_[j]);
      }
      a.x += __shfl_xor(a.x, 1); a.y += __shfl_xor(a.y, 1);
      a.z += __shfl_xor(a.z, 1); a.w += __shfl_xor(a.w, 1);
      a.x += __shfl_xor(a.x, 2); a.y += __shfl_xor(a.y, 2);
      a.z += __shfl_xor(a.z, 2); a.w += __shfl_xor(a.w, 2);
      a.x += b1q.x; a.y += b1q.y; a.z += b1q.z; a.w += b1q.w;
      float i_ = sigf(a.x), f_ = sigf(a.y), g_ = tanhf(a.z), o_ = sigf(a.w);
      c1 = fmaf(f_, c1, i_ * g_);
      float h1n = o_ * tanhf(c1);
      if (kq == 0) {
        s_h1[pp^1][u + 2*(u>>5)] = h1n;
        outrow[(size_t)t * HH + u] = h1n;
      }
      h1keep = h1n;
    }
    __syncthreads();                   // new h1 visible
  }

  // tail: h1 frozen for t >= len; parallel over kq
  for (int t = len + kq; t < TT; t += 4)
    outrow[(size_t)t * HH + u] = h1keep;
}

// ---------------------------------------------------------------------------
// In-place projection: d_out rows h1 -> logits (fp32).
// ---------------------------------------------------------------------------
__global__ __launch_bounds__(256) void proj_kernel(
    const float* __restrict__ bout, float* __restrict__ out)
{
  __shared__ float4 s_wo[(HH/4)*VOUT];   // 64 KB
  __shared__ float  s_bout[VOUT];

  const int tid  = threadIdx.x;
  const int wid  = tid >> 6;
  const int lane = tid & 63;

  for (int i = tid; i < (HH/4)*VOUT; i += 256) s_wo[i] = g_Wo4[i];
  if (tid < VOUT) s_bout[tid] = bout[tid];
  __syncthreads();

  const int PPB = (NB*TT) / 256;         // 512 rows per block
  const int start = blockIdx.x * PPB;
  for (int it = 0; it < PPB/4; ++it) {
    const int pair = start + it*4 + wid;
    float* rowp = out + (size_t)pair * HH;
    float v0 = s_bout[lane], v1 = s_bout[lane + 64];
    #pragma unroll 8
    for (int k4 = 0; k4 < HH/4; ++k4) {
      float4 h4 = *(const float4*)(rowp + k4*4);   // wave-uniform broadcast
      float4 w0 = s_wo[k4*VOUT + lane];
      float4 w1 = s_wo[k4*VOUT + lane + 64];
      v0 = fmaf(h4.x,w0.x, fmaf(h4.y,w0.y, fmaf(h4.z,w0.z, fmaf(h4.w,w0.w, v0))));
      v1 = fmaf(h4.x,w1.x, fmaf(h4.y,w1.y, fmaf(h4.z,w1.z, fmaf(h4.w,w1.w, v1))));
    }
    rowp[lane]      = v0;
    rowp[lane + 64] = v1;
  }
}

extern "C" void kernel_launch(void* const* d_in, const int* in_sizes, int n_in,
                              void* d_out, int out_size, void* d_ws, size_t ws_size,
                              hipStream_t stream) {
  const int*   src  = (const int*)  d_in[0];
  const int*   lens = (const int*)  d_in[1];
  const float* emb  = (const float*)d_in[2];
  const float* Wx0  = (const float*)d_in[3];
  const float* bx0  = (const float*)d_in[4];
  const float* Wh0  = (const float*)d_in[5];
  const float* Wx1  = (const float*)d_in[6];
  const float* bx1  = (const float*)d_in[7];
  const float* Wh1  = (const float*)d_in[8];
  const float* Wout = (const float*)d_in[9];
  const float* bout = (const float*)d_in[10];
  float* out = (float*)d_out;

  hipLaunchKernelGGL(prep_kernel, dim3(32), dim3(256), 0, stream,
                     Wx0, Wh0, Wx1, Wh1, Wout);
  hipLaunchKernelGGL(xproj_kernel, dim3(NB), dim3(256), 0, stream,
                     src, lens, emb, bx0);
  hipLaunchKernelGGL(lstm_kernel, dim3(NB), dim3(NTHR), 0, stream,
                     lens, bx1, out);
  hipLaunchKernelGGL(proj_kernel, dim3(256), dim3(256), 0, stream,
                     bout, out);
}